// Round 2
// 78.754 us; speedup vs baseline: 1.0018x; 1.0018x over previous
//
#include <hip/hip_runtime.h>

// ColorDenseCRFLoss via 32x32x16 MFMA + triangle symmetry.
// out = -1e-7/4 * sum_{n,p,q} exp(-0.5*||f_p-f_q||^2) * (seg_p . seg_q)
// P=4096 pixels/batch -> 128 tiles of 32 rows -> 32 strips of 4 tiles.
// Block (c, sp, n): 4 waves = 4 i-tiles of strip sp (phase0) and strip 31-sp
// (phase1); each wave computes 32x32 output tiles vs j-tiles jbase+c+16*t.
// Per tile-job: 1 arg MFMA (K=16 exact) + 2 seg MFMAs (K=21 padded to 32,
// hi half routed to zero page) + 16 exp2 + 16 fma into 4 partials.
// Off-diagonal tiles weight 2; strip-diagonal tiles weight 1 (full-tile sum
// is exact by symmetry of the pair value). Ping-pong 2-slot prefetch, no
// register rotation, no dynamic register-array indexing.

#define N_BATCH 4
#define IH 128
#define IW 128
#define P 4096   // 64x64 downsampled pixels per batch
#define KC 21

using short8   = __attribute__((ext_vector_type(8))) short;
using floatx16 = __attribute__((ext_vector_type(16))) float;

static constexpr float INV_SIGMA = 1.0f / 15.0f;
static constexpr float LOG2E     = 1.4426950408889634f;
static constexpr float OUT_SCALE = -1e-7f / 4.0f;

// ws layout (bytes):
//   [0,64)  zero page; argA/argB: rows x 32B; seg: rows x 48B
#define ZP_OFF   0
#define ARGA_OFF 64
#define ARGB_OFF (ARGA_OFF + N_BATCH * P * 32)
#define SEG_OFF  (ARGB_OFF + N_BATCH * P * 32)

#define NFEAT (N_BATCH * P)              // 16384
#define NSEG2 (N_BATCH * KC * P / 2)     // 172032 (2 pixels/thread)

#define CHUNKS 16

__device__ __forceinline__ ushort f2bf(float x) {  // RNE float->bf16 bits
    unsigned u = __builtin_bit_cast(unsigned, x);
    unsigned r = (u + 0x7FFFu + ((u >> 16) & 1u)) >> 16;
    return (ushort)r;
}
__device__ __forceinline__ float bf2f(ushort h) {
    return __builtin_bit_cast(float, (unsigned)h << 16);
}

__global__ void crf_prep(const float* __restrict__ img,
                         const float* __restrict__ seg,
                         char* __restrict__ wsb,
                         float* __restrict__ out)
{
    int t = blockIdx.x * blockDim.x + threadIdx.x;
    if (t < NFEAT) {
        if (t == 0) out[0] = 0.0f;
        if (t < 16) ((float*)(wsb + ZP_OFF))[t] = 0.0f;  // zero page

        int n = t >> 12;
        int p = t & (P - 1);
        int y = p >> 6, x = p & 63;

        const float* ib = img + (size_t)n * 3 * IH * IW + (size_t)(2 * y) * IW + 2 * x;
        float f0 = ib[0] * INV_SIGMA;
        float f1 = ib[IH * IW] * INV_SIGMA;
        float f2 = ib[2 * IH * IW] * INV_SIGMA;
        float h = 0.5f * (f0 * f0 + f1 * f1 + f2 * f2);

        float fa0 = f0 * LOG2E, fa1 = f1 * LOG2E, fa2 = f2 * LOG2E;
        ushort ah0 = f2bf(fa0), ah1 = f2bf(fa1), ah2 = f2bf(fa2);
        ushort al0 = f2bf(fa0 - bf2f(ah0));
        ushort al1 = f2bf(fa1 - bf2f(ah1));
        ushort al2 = f2bf(fa2 - bf2f(ah2));
        float nhL = -h * LOG2E;
        ushort nhh = f2bf(nhL), nhl = f2bf(nhL - bf2f(nhh));
        ushort bh0 = f2bf(f0), bh1 = f2bf(f1), bh2 = f2bf(f2);
        ushort bl0 = f2bf(f0 - bf2f(bh0));
        ushort bl1 = f2bf(f1 - bf2f(bh1));
        ushort bl2 = f2bf(f2 - bf2f(bh2));
        float hL = h * LOG2E;
        ushort hbh = f2bf(hL), hbl = f2bf(hL - bf2f(hbh));

        const ushort ONE = 0x3F80, NEG1 = 0xBF80;
        // dot(argA_p, argB_q) = log2e * (f_p.f_q - h_p - h_q), exactly K=16
        ushort rA[16] = {ah0, ah1, ah2, ah0, ah1, ah2, al0, al1, al2, al0, al1, al2,
                         nhh, nhl, NEG1, NEG1};
        ushort rB[16] = {bh0, bh1, bh2, bl0, bl1, bl2, bh0, bh1, bh2, bl0, bl1, bl2,
                         ONE, ONE, hbh, hbl};

        short8 vA0, vA1, vB0, vB1;
#pragma unroll
        for (int j = 0; j < 8; ++j) {
            vA0[j] = (short)rA[j];     vA1[j] = (short)rA[8 + j];
            vB0[j] = (short)rB[j];     vB1[j] = (short)rB[8 + j];
        }
        short8* dA = (short8*)(wsb + ARGA_OFF + (size_t)t * 32);
        dA[0] = vA0; dA[1] = vA1;
        short8* dB = (short8*)(wsb + ARGB_OFF + (size_t)t * 32);
        dB[0] = vB0; dB[1] = vB1;

        char* sp = wsb + SEG_OFF + (size_t)t * 48;   // zero seg pad k=21..23
        *(ushort*)(sp + 42) = 0;
        *(uint*)(sp + 44) = 0;
    } else if (t < NFEAT + NSEG2) {
        int u = t - NFEAT;
        int pp = (u & 2047) * 2;     // pixel pair base (even)
        int nk = u >> 11;            // n*21 + k
        int n = nk / 21;
        int k = nk - n * 21;
        int y = pp >> 6, x0 = pp & 63;

        const float* r0 = seg + (size_t)nk * IH * IW + (size_t)(2 * y) * IW + 2 * x0;
        float4 a = *(const float4*)r0;
        float4 b = *(const float4*)(r0 + IW);
        float v0 = 0.25f * ((a.x + a.y) + (b.x + b.y));
        float v1 = 0.25f * ((a.z + a.w) + (b.z + b.w));
        char* d = wsb + SEG_OFF + (size_t)(n * P + pp) * 48 + k * 2;
        *(ushort*)d = f2bf(v0);
        *(ushort*)(d + 48) = f2bf(v1);
    }
}

__global__ __launch_bounds__(256, 4) void crf_pair(const char* __restrict__ wsb,
                                                   float* __restrict__ out)
{
    const int n    = blockIdx.z;
    const int sp   = blockIdx.y;          // strip pair [0,16): strips sp, 31-sp
    const int c    = blockIdx.x;          // j-chunk [0,16)
    const int wave = threadIdx.x >> 6;    // i-tile within strip [0,4)
    const int lane = threadIdx.x & 63;
    const int l32  = lane & 31;
    const int l5   = lane >> 5;           // k-half select

    const char* argA = wsb + ARGA_OFF + (size_t)n * P * 32;
    const char* argB = wsb + ARGB_OFF + (size_t)n * P * 32;
    const char* segT = wsb + SEG_OFF  + (size_t)n * P * 48;
    const char* zp   = wsb + ZP_OFF;

    // B-side per-lane bases; j-tile strides 1024B (arg) / 1536B (seg)
    const char* bBa = argB + l32 * 32 + l5 * 16;
    const char* bBs = segT + l32 * 48 + l5 * 16;
    const int maskH = l5 ? 0 : ~0;        // hi seg half: k>=24 is zero pad
    const char* bBh = l5 ? zp : (segT + l32 * 48 + 32);

    const floatx16 zc = {0.f,0.f,0.f,0.f,0.f,0.f,0.f,0.f,
                         0.f,0.f,0.f,0.f,0.f,0.f,0.f,0.f};

    short8 afA, afL, afH;                 // A fragments for current phase

    float m0=0.f, m1=0.f, m2=0.f, m3=0.f; // weight-2 partials
    float d0=0.f, d1=0.f, d2=0.f, d3=0.f; // weight-1 (diag tile) partials

    auto jobM = [&](short8 ba, short8 bl, short8 bh) {
        floatx16 ar = __builtin_amdgcn_mfma_f32_32x32x16_bf16(afA, ba, zc, 0, 0, 0);
        floatx16 g  = __builtin_amdgcn_mfma_f32_32x32x16_bf16(afL, bl, zc, 0, 0, 0);
        g = __builtin_amdgcn_mfma_f32_32x32x16_bf16(afH, bh, g, 0, 0, 0);
#pragma unroll
        for (int r = 0; r < 16; ++r) {
            float t = __builtin_amdgcn_exp2f(ar[r]) * g[r];
            if ((r & 3) == 0) m0 += t;
            else if ((r & 3) == 1) m1 += t;
            else if ((r & 3) == 2) m2 += t;
            else m3 += t;
        }
    };
    auto jobD = [&](short8 ba, short8 bl, short8 bh) {
        floatx16 ar = __builtin_amdgcn_mfma_f32_32x32x16_bf16(afA, ba, zc, 0, 0, 0);
        floatx16 g  = __builtin_amdgcn_mfma_f32_32x32x16_bf16(afL, bl, zc, 0, 0, 0);
        g = __builtin_amdgcn_mfma_f32_32x32x16_bf16(afH, bh, g, 0, 0, 0);
#pragma unroll
        for (int r = 0; r < 16; ++r) {
            float t = __builtin_amdgcn_exp2f(ar[r]) * g[r];
            if ((r & 3) == 0) d0 += t;
            else if ((r & 3) == 1) d1 += t;
            else if ((r & 3) == 2) d2 += t;
            else d3 += t;
        }
    };

    auto load_A = [&](int ti) {
        int rr = ti * 32 + l32;
        afA = *(const short8*)(argA + rr * 32 + l5 * 16);
        afL = *(const short8*)(segT + rr * 48 + l5 * 16);
        afH = l5 ? *(const short8*)zp : *(const short8*)(segT + rr * 48 + 32);
    };

    // Main phase: j-tiles jbase+c, +CHUNKS, ... while index < jbase+cnt.
    // 2-slot ping-pong; reload a slot right after its MFMAs consumed it.
    auto run_main = [&](int jbase, int cnt) {
        if (cnt <= c) return;
        int nj = (cnt - c + CHUNKS - 1) / CHUNKS;
        int j0 = jbase + c;
        int oA0 = j0 * 1024, oS0 = j0 * 1536;
        int oA1 = oA0 + CHUNKS * 1024, oS1 = oS0 + CHUNKS * 1536;
        short8 a0 = *(const short8*)(bBa + oA0);
        short8 l0 = *(const short8*)(bBs + oS0);
        short8 h0 = *(const short8*)(bBh + (oS0 & maskH));
        short8 a1 = a0, l1 = l0, h1 = h0;
        if (nj > 1) {
            a1 = *(const short8*)(bBa + oA1);
            l1 = *(const short8*)(bBs + oS1);
            h1 = *(const short8*)(bBh + (oS1 & maskH));
        }
        for (int t = 0; t < nj; t += 2) {
            jobM(a0, l0, h0);
            if (t + 2 < nj) {
                oA0 += 2 * CHUNKS * 1024; oS0 += 2 * CHUNKS * 1536;
                a0 = *(const short8*)(bBa + oA0);
                l0 = *(const short8*)(bBs + oS0);
                h0 = *(const short8*)(bBh + (oS0 & maskH));
            }
            if (t + 1 < nj) {
                jobM(a1, l1, h1);
                if (t + 3 < nj) {
                    oA1 += 2 * CHUNKS * 1024; oS1 += 2 * CHUNKS * 1536;
                    a1 = *(const short8*)(bBa + oA1);
                    l1 = *(const short8*)(bBs + oS1);
                    h1 = *(const short8*)(bBh + (oS1 & maskH));
                }
            }
        }
    };

    // Strip-diagonal 4x4 tile block: wave ii handles j-tiles [4s+ii, 4s+4).
    auto run_edge = [&](int s) {
        for (int jj = wave; jj < 4; ++jj) {
            int j = 4 * s + jj;
            int oA = j * 1024, oS = j * 1536;
            short8 ba = *(const short8*)(bBa + oA);
            short8 bl = *(const short8*)(bBs + oS);
            short8 bh = *(const short8*)(bBh + (oS & maskH));
            if (jj == wave) jobD(ba, bl, bh);   // diag tile, weight 1 (symmetric)
            else           jobM(ba, bl, bh);    // off-diag, weight 2
        }
    };

    const int s0 = sp, s1 = 31 - sp;

    load_A(4 * s0 + wave);
    run_main(4 * s0 + 4, 124 - 4 * sp);
    if (c == CHUNKS - 1) run_edge(s0);

    load_A(4 * s1 + wave);
    run_main(4 * s1 + 4, 4 * sp);
    if (c == CHUNKS - 2) run_edge(s1);

    float part = 2.0f * ((m0 + m1) + (m2 + m3)) + ((d0 + d1) + (d2 + d3));
#pragma unroll
    for (int off = 32; off > 0; off >>= 1)
        part += __shfl_down(part, off, 64);
    __shared__ float wsum[4];
    if (lane == 0) wsum[wave] = part;
    __syncthreads();
    if (threadIdx.x == 0)
        atomicAdd(out, ((wsum[0] + wsum[1]) + (wsum[2] + wsum[3])) * OUT_SCALE);
}

extern "C" void kernel_launch(void* const* d_in, const int* in_sizes, int n_in,
                              void* d_out, int out_size, void* d_ws, size_t ws_size,
                              hipStream_t stream)
{
    const float* images = (const float*)d_in[0];   // [4,3,128,128]
    const float* segm   = (const float*)d_in[1];   // [4,21,128,128]
    float* out = (float*)d_out;                    // [1]
    char* wsb = (char*)d_ws;                       // ~1.79 MB used

    int prep_threads = NFEAT + NSEG2;
    crf_prep<<<dim3((prep_threads + 255) / 256), dim3(256), 0, stream>>>(
        images, segm, wsb, out);
    crf_pair<<<dim3(CHUNKS, 16, N_BATCH), dim3(256), 0, stream>>>(wsb, out);
}

// Round 3
// 71.014 us; speedup vs baseline: 1.1110x; 1.1090x over previous
//
#include <hip/hip_runtime.h>

// ColorDenseCRFLoss via 32x32x16 MFMA + triangle symmetry.
// out = -1e-7/4 * sum_{n,p,q} exp(-0.5*||f_p-f_q||^2) * (seg_p . seg_q)
// R2 change: kill the 1024-block same-address atomicAdd storm. Each block
// stores its partial to ws[PART_OFF + blockLinear]; a 1-block crf_reduce
// kernel sums the 1024 partials and writes out. Theory: same-address
// device-scope fp32 atomics from 1024 blocks serialize at the coherence
// point (~15-30us), explaining dur_us invariance across R0/R2 kernels.

#define N_BATCH 4
#define IH 128
#define IW 128
#define P 4096   // 64x64 downsampled pixels per batch
#define KC 21

using short8   = __attribute__((ext_vector_type(8))) short;
using floatx16 = __attribute__((ext_vector_type(16))) float;

static constexpr float INV_SIGMA = 1.0f / 15.0f;
static constexpr float LOG2E     = 1.4426950408889634f;
static constexpr float OUT_SCALE = -1e-7f / 4.0f;

// ws layout (bytes):
//   [0,64)  zero page; argA/argB: rows x 32B; seg: rows x 48B; partials
#define ZP_OFF   0
#define ARGA_OFF 64
#define ARGB_OFF (ARGA_OFF + N_BATCH * P * 32)
#define SEG_OFF  (ARGB_OFF + N_BATCH * P * 32)
#define PART_OFF (SEG_OFF + N_BATCH * P * 48)   // 1,835,072 (64B aligned)

#define NFEAT (N_BATCH * P)              // 16384
#define NSEG2 (N_BATCH * KC * P / 2)     // 172032 (2 pixels/thread)

#define CHUNKS 16
#define NBLOCKS (CHUNKS * 16 * N_BATCH)  // 1024 crf_pair blocks

__device__ __forceinline__ ushort f2bf(float x) {  // RNE float->bf16 bits
    unsigned u = __builtin_bit_cast(unsigned, x);
    unsigned r = (u + 0x7FFFu + ((u >> 16) & 1u)) >> 16;
    return (ushort)r;
}
__device__ __forceinline__ float bf2f(ushort h) {
    return __builtin_bit_cast(float, (unsigned)h << 16);
}

__global__ void crf_prep(const float* __restrict__ img,
                         const float* __restrict__ seg,
                         char* __restrict__ wsb)
{
    int t = blockIdx.x * blockDim.x + threadIdx.x;
    if (t < NFEAT) {
        if (t < 16) ((float*)(wsb + ZP_OFF))[t] = 0.0f;  // zero page

        int n = t >> 12;
        int p = t & (P - 1);
        int y = p >> 6, x = p & 63;

        const float* ib = img + (size_t)n * 3 * IH * IW + (size_t)(2 * y) * IW + 2 * x;
        float f0 = ib[0] * INV_SIGMA;
        float f1 = ib[IH * IW] * INV_SIGMA;
        float f2 = ib[2 * IH * IW] * INV_SIGMA;
        float h = 0.5f * (f0 * f0 + f1 * f1 + f2 * f2);

        float fa0 = f0 * LOG2E, fa1 = f1 * LOG2E, fa2 = f2 * LOG2E;
        ushort ah0 = f2bf(fa0), ah1 = f2bf(fa1), ah2 = f2bf(fa2);
        ushort al0 = f2bf(fa0 - bf2f(ah0));
        ushort al1 = f2bf(fa1 - bf2f(ah1));
        ushort al2 = f2bf(fa2 - bf2f(ah2));
        float nhL = -h * LOG2E;
        ushort nhh = f2bf(nhL), nhl = f2bf(nhL - bf2f(nhh));
        ushort bh0 = f2bf(f0), bh1 = f2bf(f1), bh2 = f2bf(f2);
        ushort bl0 = f2bf(f0 - bf2f(bh0));
        ushort bl1 = f2bf(f1 - bf2f(bh1));
        ushort bl2 = f2bf(f2 - bf2f(bh2));
        float hL = h * LOG2E;
        ushort hbh = f2bf(hL), hbl = f2bf(hL - bf2f(hbh));

        const ushort ONE = 0x3F80, NEG1 = 0xBF80;
        // dot(argA_p, argB_q) = log2e * (f_p.f_q - h_p - h_q), exactly K=16
        ushort rA[16] = {ah0, ah1, ah2, ah0, ah1, ah2, al0, al1, al2, al0, al1, al2,
                         nhh, nhl, NEG1, NEG1};
        ushort rB[16] = {bh0, bh1, bh2, bl0, bl1, bl2, bh0, bh1, bh2, bl0, bl1, bl2,
                         ONE, ONE, hbh, hbl};

        short8 vA0, vA1, vB0, vB1;
#pragma unroll
        for (int j = 0; j < 8; ++j) {
            vA0[j] = (short)rA[j];     vA1[j] = (short)rA[8 + j];
            vB0[j] = (short)rB[j];     vB1[j] = (short)rB[8 + j];
        }
        short8* dA = (short8*)(wsb + ARGA_OFF + (size_t)t * 32);
        dA[0] = vA0; dA[1] = vA1;
        short8* dB = (short8*)(wsb + ARGB_OFF + (size_t)t * 32);
        dB[0] = vB0; dB[1] = vB1;

        char* sp = wsb + SEG_OFF + (size_t)t * 48;   // zero seg pad k=21..23
        *(ushort*)(sp + 42) = 0;
        *(uint*)(sp + 44) = 0;
    } else if (t < NFEAT + NSEG2) {
        int u = t - NFEAT;
        int pp = (u & 2047) * 2;     // pixel pair base (even)
        int nk = u >> 11;            // n*21 + k
        int n = nk / 21;
        int k = nk - n * 21;
        int y = pp >> 6, x0 = pp & 63;

        const float* r0 = seg + (size_t)nk * IH * IW + (size_t)(2 * y) * IW + 2 * x0;
        float4 a = *(const float4*)r0;
        float4 b = *(const float4*)(r0 + IW);
        float v0 = 0.25f * ((a.x + a.y) + (b.x + b.y));
        float v1 = 0.25f * ((a.z + a.w) + (b.z + b.w));
        char* d = wsb + SEG_OFF + (size_t)(n * P + pp) * 48 + k * 2;
        *(ushort*)d = f2bf(v0);
        *(ushort*)(d + 48) = f2bf(v1);
    }
}

__global__ __launch_bounds__(256, 4) void crf_pair(char* __restrict__ wsb)
{
    const int n    = blockIdx.z;
    const int sp   = blockIdx.y;          // strip pair [0,16): strips sp, 31-sp
    const int c    = blockIdx.x;          // j-chunk [0,16)
    const int wave = threadIdx.x >> 6;    // i-tile within strip [0,4)
    const int lane = threadIdx.x & 63;
    const int l32  = lane & 31;
    const int l5   = lane >> 5;           // k-half select

    const char* argA = wsb + ARGA_OFF + (size_t)n * P * 32;
    const char* argB = wsb + ARGB_OFF + (size_t)n * P * 32;
    const char* segT = wsb + SEG_OFF  + (size_t)n * P * 48;
    const char* zp   = wsb + ZP_OFF;

    // B-side per-lane bases; j-tile strides 1024B (arg) / 1536B (seg)
    const char* bBa = argB + l32 * 32 + l5 * 16;
    const char* bBs = segT + l32 * 48 + l5 * 16;
    const int maskH = l5 ? 0 : ~0;        // hi seg half: k>=24 is zero pad
    const char* bBh = l5 ? zp : (segT + l32 * 48 + 32);

    const floatx16 zc = {0.f,0.f,0.f,0.f,0.f,0.f,0.f,0.f,
                         0.f,0.f,0.f,0.f,0.f,0.f,0.f,0.f};

    short8 afA, afL, afH;                 // A fragments for current phase

    float m0=0.f, m1=0.f, m2=0.f, m3=0.f; // weight-2 partials
    float d0=0.f, d1=0.f, d2=0.f, d3=0.f; // weight-1 (diag tile) partials

    auto jobM = [&](short8 ba, short8 bl, short8 bh) {
        floatx16 ar = __builtin_amdgcn_mfma_f32_32x32x16_bf16(afA, ba, zc, 0, 0, 0);
        floatx16 g  = __builtin_amdgcn_mfma_f32_32x32x16_bf16(afL, bl, zc, 0, 0, 0);
        g = __builtin_amdgcn_mfma_f32_32x32x16_bf16(afH, bh, g, 0, 0, 0);
#pragma unroll
        for (int r = 0; r < 16; ++r) {
            float t = __builtin_amdgcn_exp2f(ar[r]) * g[r];
            if ((r & 3) == 0) m0 += t;
            else if ((r & 3) == 1) m1 += t;
            else if ((r & 3) == 2) m2 += t;
            else m3 += t;
        }
    };
    auto jobD = [&](short8 ba, short8 bl, short8 bh) {
        floatx16 ar = __builtin_amdgcn_mfma_f32_32x32x16_bf16(afA, ba, zc, 0, 0, 0);
        floatx16 g  = __builtin_amdgcn_mfma_f32_32x32x16_bf16(afL, bl, zc, 0, 0, 0);
        g = __builtin_amdgcn_mfma_f32_32x32x16_bf16(afH, bh, g, 0, 0, 0);
#pragma unroll
        for (int r = 0; r < 16; ++r) {
            float t = __builtin_amdgcn_exp2f(ar[r]) * g[r];
            if ((r & 3) == 0) d0 += t;
            else if ((r & 3) == 1) d1 += t;
            else if ((r & 3) == 2) d2 += t;
            else d3 += t;
        }
    };

    auto load_A = [&](int ti) {
        int rr = ti * 32 + l32;
        afA = *(const short8*)(argA + rr * 32 + l5 * 16);
        afL = *(const short8*)(segT + rr * 48 + l5 * 16);
        afH = l5 ? *(const short8*)zp : *(const short8*)(segT + rr * 48 + 32);
    };

    // Main phase: j-tiles jbase+c, +CHUNKS, ... while index < jbase+cnt.
    // 2-slot ping-pong; reload a slot right after its MFMAs consumed it.
    auto run_main = [&](int jbase, int cnt) {
        if (cnt <= c) return;
        int nj = (cnt - c + CHUNKS - 1) / CHUNKS;
        int j0 = jbase + c;
        int oA0 = j0 * 1024, oS0 = j0 * 1536;
        int oA1 = oA0 + CHUNKS * 1024, oS1 = oS0 + CHUNKS * 1536;
        short8 a0 = *(const short8*)(bBa + oA0);
        short8 l0 = *(const short8*)(bBs + oS0);
        short8 h0 = *(const short8*)(bBh + (oS0 & maskH));
        short8 a1 = a0, l1 = l0, h1 = h0;
        if (nj > 1) {
            a1 = *(const short8*)(bBa + oA1);
            l1 = *(const short8*)(bBs + oS1);
            h1 = *(const short8*)(bBh + (oS1 & maskH));
        }
        for (int t = 0; t < nj; t += 2) {
            jobM(a0, l0, h0);
            if (t + 2 < nj) {
                oA0 += 2 * CHUNKS * 1024; oS0 += 2 * CHUNKS * 1536;
                a0 = *(const short8*)(bBa + oA0);
                l0 = *(const short8*)(bBs + oS0);
                h0 = *(const short8*)(bBh + (oS0 & maskH));
            }
            if (t + 1 < nj) {
                jobM(a1, l1, h1);
                if (t + 3 < nj) {
                    oA1 += 2 * CHUNKS * 1024; oS1 += 2 * CHUNKS * 1536;
                    a1 = *(const short8*)(bBa + oA1);
                    l1 = *(const short8*)(bBs + oS1);
                    h1 = *(const short8*)(bBh + (oS1 & maskH));
                }
            }
        }
    };

    // Strip-diagonal 4x4 tile block: wave ii handles j-tiles [4s+ii, 4s+4).
    auto run_edge = [&](int s) {
        for (int jj = wave; jj < 4; ++jj) {
            int j = 4 * s + jj;
            int oA = j * 1024, oS = j * 1536;
            short8 ba = *(const short8*)(bBa + oA);
            short8 bl = *(const short8*)(bBs + oS);
            short8 bh = *(const short8*)(bBh + (oS & maskH));
            if (jj == wave) jobD(ba, bl, bh);   // diag tile, weight 1 (symmetric)
            else           jobM(ba, bl, bh);    // off-diag, weight 2
        }
    };

    const int s0 = sp, s1 = 31 - sp;

    load_A(4 * s0 + wave);
    run_main(4 * s0 + 4, 124 - 4 * sp);
    if (c == CHUNKS - 1) run_edge(s0);

    load_A(4 * s1 + wave);
    run_main(4 * s1 + 4, 4 * sp);
    if (c == CHUNKS - 2) run_edge(s1);

    float part = 2.0f * ((m0 + m1) + (m2 + m3)) + ((d0 + d1) + (d2 + d3));
#pragma unroll
    for (int off = 32; off > 0; off >>= 1)
        part += __shfl_down(part, off, 64);
    __shared__ float wsum[4];
    if (lane == 0) wsum[wave] = part;
    __syncthreads();
    if (threadIdx.x == 0) {
        int blin = (n * 16 + sp) * CHUNKS + c;   // [0, NBLOCKS)
        ((float*)(wsb + PART_OFF))[blin] =
            (wsum[0] + wsum[1]) + (wsum[2] + wsum[3]);
    }
}

__global__ void crf_reduce(const char* __restrict__ wsb,
                           float* __restrict__ out)
{
    const float* part = (const float*)(wsb + PART_OFF);
    int t = threadIdx.x;                 // 256 threads
    float s = (part[t] + part[t + 256]) + (part[t + 512] + part[t + 768]);
#pragma unroll
    for (int off = 32; off > 0; off >>= 1)
        s += __shfl_down(s, off, 64);
    __shared__ float wsum[4];
    if ((t & 63) == 0) wsum[t >> 6] = s;
    __syncthreads();
    if (t == 0)
        out[0] = ((wsum[0] + wsum[1]) + (wsum[2] + wsum[3])) * OUT_SCALE;
}

extern "C" void kernel_launch(void* const* d_in, const int* in_sizes, int n_in,
                              void* d_out, int out_size, void* d_ws, size_t ws_size,
                              hipStream_t stream)
{
    const float* images = (const float*)d_in[0];   // [4,3,128,128]
    const float* segm   = (const float*)d_in[1];   // [4,21,128,128]
    float* out = (float*)d_out;                    // [1]
    char* wsb = (char*)d_ws;                       // ~1.84 MB used

    int prep_threads = NFEAT + NSEG2;
    crf_prep<<<dim3((prep_threads + 255) / 256), dim3(256), 0, stream>>>(
        images, segm, wsb);
    crf_pair<<<dim3(CHUNKS, 16, N_BATCH), dim3(256), 0, stream>>>(wsb);
    crf_reduce<<<dim3(1), dim3(256), 0, stream>>>(wsb, out);
}